// Round 1
// baseline (540.722 us; speedup 1.0000x reference)
//
#include <hip/hip_runtime.h>

#define NSER 8192
#define NTS  400
#define NO   9
#define LOG2PI_F 1.8378770664093453f

__device__ __forceinline__ float frcp(float x){ return __builtin_amdgcn_rcpf(x); }

__global__ void zero_kernel(float* out, int n){
    int i = blockIdx.x*blockDim.x + threadIdx.x;
    if (i < n) out[i] = 0.f;
}

// One thread = one series. Full 400-step regime-switching KF in registers.
// L1 path: Woodbury with diagonal W^T D^-1 W  -> symmetric 3x3 inverse.
// L2 path: Sherman-Morrison rank-1.
__global__ __launch_bounds__(64, 1)
void rskf_kernel(const float* __restrict__ y,   // (N, NT, O)
                 const float* __restrict__ B1,  // 3x3
                 const float* __restrict__ B2,  // 1
                 const float* __restrict__ l1,  // 6
                 const float* __restrict__ l2,  // 8
                 const float* __restrict__ lq,  // 4
                 const float* __restrict__ lr,  // 9
                 const float* __restrict__ g0p, // 1
                 const float* __restrict__ gc,  // 3
                 float* __restrict__ out)
{
    const int n = blockIdx.x*64 + (int)threadIdx.x;

    // ---- uniform parameter prep (scalar loads, once) ----
    float Bm[3][3];
    #pragma unroll
    for (int i=0;i<3;++i)
        #pragma unroll
        for (int j=0;j<3;++j) Bm[i][j] = B1[i*3+j];
    const float b2 = B2[0];
    float qd[4];
    #pragma unroll
    for (int i=0;i<4;++i) qd[i] = __expf(lq[i]);

    float c[9];
    c[0]=1.f; c[1]=l1[0]; c[2]=l1[1];
    c[3]=1.f; c[4]=l1[2]; c[5]=l1[3];
    c[6]=1.f; c[7]=l1[4]; c[8]=l1[5];
    float mv[9]; mv[0]=1.f;
    #pragma unroll
    for (int o=1;o<9;++o) mv[o]=l2[o-1];

    float invD[9], w1c[9], wmc[9];
    float logdetD = 0.f;
    #pragma unroll
    for (int o=0;o<9;++o){
        float D  = __expf(lr[o]) + 1e-6f;   // R diag + jitter
        logdetD += __logf(D);
        float id = 1.f/D;
        invD[o]=id; w1c[o]=c[o]*id; wmc[o]=mv[o]*id;
    }
    const float s0 = c[0]*w1c[0]+c[1]*w1c[1]+c[2]*w1c[2];
    const float s1 = c[3]*w1c[3]+c[4]*w1c[4]+c[5]*w1c[5];
    const float s2 = c[6]*w1c[6]+c[7]*w1c[7]+c[8]*w1c[8];
    float smm = 0.f;
    #pragma unroll
    for (int o=0;o<9;++o) smm += mv[o]*wmc[o];
    const float invs0=1.f/s0, invs1=1.f/s1, invs2=1.f/s2;
    const float C2f = 9.f*LOG2PI_F + logdetD;                         // logdet const, regime 2
    const float C1f = C2f + __logf(s0)+__logf(s1)+__logf(s2);         // + logdet(S), regime 1
    const float g0 = g0p[0];
    const float gc0=gc[0], gc1=gc[1], gc2=gc[2];

    // ---- state ----
    float prob1=0.99f, prob2=0.01f;
    float eta0=0.f, eta1v=0.f, eta2v=0.f, eta3=0.f;
    float P[4][4];
    #pragma unroll
    for (int i=0;i<4;++i)
        #pragma unroll
        for (int j=0;j<4;++j) P[i][j] = (i==j)?1000.f:0.f;

    const float* __restrict__ yp = y + (size_t)n*(NTS*NO);
    float ynx[9];
    #pragma unroll
    for (int o=0;o<9;++o) ynx[o]=yp[o];
    float acc=0.f;

    for (int t=0;t<NTS;++t){
        // consume prefetched y_t, prefetch y_{t+1}
        float yc[9];
        #pragma unroll
        for (int o=0;o<9;++o) yc[o]=ynx[o];
        const int tn = (t+1<NTS)?(t+1):t;
        const float* ypn = yp + tn*NO;
        #pragma unroll
        for (int o=0;o<9;++o) ynx[o]=ypn[o];

        // regime transition probability
        float logit = g0 + gc0*eta0 + gc1*eta1v + gc2*eta2v;
        float p11 = frcp(1.f + __expf(-logit));
        float p12 = 1.f - p11;

        // predict mean: eta_pred = B eta (block diagonal)
        float ep0 = Bm[0][0]*eta0 + Bm[0][1]*eta1v + Bm[0][2]*eta2v;
        float ep1 = Bm[1][0]*eta0 + Bm[1][1]*eta1v + Bm[1][2]*eta2v;
        float ep2 = Bm[2][0]*eta0 + Bm[2][1]*eta1v + Bm[2][2]*eta2v;
        float ep3 = b2*eta3;

        // predict covariance: Pp = B P B^T + Q
        float Tm[4][4];
        #pragma unroll
        for (int i=0;i<3;++i)
            #pragma unroll
            for (int j=0;j<4;++j)
                Tm[i][j] = Bm[i][0]*P[0][j] + Bm[i][1]*P[1][j] + Bm[i][2]*P[2][j];
        #pragma unroll
        for (int j=0;j<4;++j) Tm[3][j] = b2*P[3][j];
        float Pp[4][4];
        #pragma unroll
        for (int i=0;i<4;++i)
            #pragma unroll
            for (int j=i;j<4;++j){
                float v;
                if (j<3) v = Tm[i][0]*Bm[j][0] + Tm[i][1]*Bm[j][1] + Tm[i][2]*Bm[j][2];
                else     v = Tm[i][3]*b2;
                Pp[i][j]=v; Pp[j][i]=v;
            }
        Pp[0][0]+=qd[0]; Pp[1][1]+=qd[1]; Pp[2][2]+=qd[2]; Pp[3][3]+=qd[3];

        // ================= regime 1 (Woodbury, rank-3 disjoint) =================
        float v1[9];
        v1[0]=yc[0]-c[0]*ep0; v1[1]=yc[1]-c[1]*ep0; v1[2]=yc[2]-c[2]*ep0;
        v1[3]=yc[3]-c[3]*ep1; v1[4]=yc[4]-c[4]*ep1; v1[5]=yc[5]-c[5]*ep1;
        v1[6]=yc[6]-c[6]*ep2; v1[7]=yc[7]-c[7]*ep2; v1[8]=yc[8]-c[8]*ep2;
        float u0 = w1c[0]*v1[0]+w1c[1]*v1[1]+w1c[2]*v1[2];
        float u1 = w1c[3]*v1[3]+w1c[4]*v1[4]+w1c[5]*v1[5];
        float u2 = w1c[6]*v1[6]+w1c[7]*v1[7]+w1c[8]*v1[8];
        float t0 = 0.f;
        #pragma unroll
        for (int o=0;o<9;++o) t0 += invD[o]*v1[o]*v1[o];
        float ub0=u0*invs0, ub1=u1*invs1, ub2=u2*invs2;
        // A3 = P3 + S^-1 ; M1 = A3^-1 (symmetric 3x3)
        float a00=Pp[0][0]+invs0, a01=Pp[0][1], a02=Pp[0][2];
        float a11=Pp[1][1]+invs1, a12=Pp[1][2], a22=Pp[2][2]+invs2;
        float i00 = a11*a22 - a12*a12;
        float i01 = a02*a12 - a01*a22;
        float i02 = a01*a12 - a02*a11;
        float det = a00*i00 + a01*i01 + a02*i02;
        float i11 = a00*a22 - a02*a02;
        float i12 = a01*a02 - a00*a12;
        float i22 = a00*a11 - a01*a01;
        float idet = frcp(det);
        float m00=i00*idet, m01=i01*idet, m02=i02*idet;
        float m11=i11*idet, m12=i12*idet, m22=i22*idet;
        float A0 = m00*ub0 + m01*ub1 + m02*ub2;   // a1 = M1 * (S^-1 u)
        float A1 = m01*ub0 + m11*ub1 + m12*ub2;
        float A2 = m02*ub0 + m12*ub1 + m22*ub2;
        float q1 = t0 - (u0*ub0+u1*ub1+u2*ub2) + (ub0*A0+ub1*A1+ub2*A2);
        float ll1 = -0.5f*(q1 + C1f + __logf(det));

        float e1[4];
        e1[0]=ep0 + Pp[0][0]*A0+Pp[0][1]*A1+Pp[0][2]*A2;
        e1[1]=ep1 + Pp[1][0]*A0+Pp[1][1]*A1+Pp[1][2]*A2;
        e1[2]=ep2 + Pp[2][0]*A0+Pp[2][1]*A1+Pp[2][2]*A2;
        e1[3]=ep3 + Pp[3][0]*A0+Pp[3][1]*A1+Pp[3][2]*A2;
        float T1[4][3];
        #pragma unroll
        for (int i=0;i<4;++i){
            T1[i][0]=Pp[i][0]*m00+Pp[i][1]*m01+Pp[i][2]*m02;
            T1[i][1]=Pp[i][0]*m01+Pp[i][1]*m11+Pp[i][2]*m12;
            T1[i][2]=Pp[i][0]*m02+Pp[i][1]*m12+Pp[i][2]*m22;
        }
        float P1[4][4];
        #pragma unroll
        for (int i=0;i<4;++i)
            #pragma unroll
            for (int j=i;j<4;++j){
                float v = Pp[i][j] - (T1[i][0]*Pp[j][0]+T1[i][1]*Pp[j][1]+T1[i][2]*Pp[j][2]);
                P1[i][j]=v; P1[j][i]=v;
            }

        // ================= regime 2 (Sherman-Morrison, rank-1) =================
        float beta = Pp[3][3];
        float v2[9];
        #pragma unroll
        for (int o=0;o<9;++o) v2[o]=yc[o]-mv[o]*ep3;
        float uu=0.f, t02=0.f;
        #pragma unroll
        for (int o=0;o<9;++o){ uu += wmc[o]*v2[o]; t02 += invD[o]*v2[o]*v2[o]; }
        float denom = 1.f + beta*smm;
        float iden  = frcp(denom);
        float q2  = t02 - beta*uu*uu*iden;
        float ll2 = -0.5f*(q2 + C2f + __logf(denom));
        float g2v = uu*iden;
        float e2[4];
        e2[0]=ep0+Pp[0][3]*g2v; e2[1]=ep1+Pp[1][3]*g2v;
        e2[2]=ep2+Pp[2][3]*g2v; e2[3]=ep3+Pp[3][3]*g2v;
        float k2 = smm*iden;
        float P2[4][4];
        #pragma unroll
        for (int i=0;i<4;++i)
            #pragma unroll
            for (int j=i;j<4;++j){
                float v = Pp[i][j] - k2*Pp[i][3]*Pp[j][3];
                P2[i][j]=v; P2[j][i]=v;
            }

        // ================= IMM mixing =================
        float lik1=__expf(ll1), lik2=__expf(ll2);
        float num1 = lik1*(prob1*p11);              // p21 = 0
        float num2 = lik2*(prob1*p12 + prob2);      // p22 = 1
        float marg = num1+num2+1e-9f;
        acc -= __logf(marg);
        float imarg = frcp(marg);
        float pt1 = num1*imarg, pt2 = num2*imarg;
        float et[4];
        #pragma unroll
        for (int i=0;i<4;++i) et[i]=pt1*e1[i]+pt2*e2[i];
        float d1[4], d2[4];
        #pragma unroll
        for (int i=0;i<4;++i){ d1[i]=e1[i]-et[i]; d2[i]=e2[i]-et[i]; }
        #pragma unroll
        for (int i=0;i<4;++i)
            #pragma unroll
            for (int j=i;j<4;++j){
                float v = pt1*(P1[i][j]+d1[i]*d1[j]) + pt2*(P2[i][j]+d2[i]*d2[j]);
                P[i][j]=v; P[j][i]=v;
            }
        prob1=pt1; prob2=pt2;
        eta0=et[0]; eta1v=et[1]; eta2v=et[2]; eta3=et[3];
    }

    // wave64 reduce + one atomic per block (block == one wave)
    #pragma unroll
    for (int off=32; off>0; off>>=1) acc += __shfl_down(acc, off);
    if (threadIdx.x==0) atomicAdd(out, acc);
}

extern "C" void kernel_launch(void* const* d_in, const int* in_sizes, int n_in,
                              void* d_out, int out_size, void* d_ws, size_t ws_size,
                              hipStream_t stream) {
    (void)in_sizes; (void)n_in; (void)d_ws; (void)ws_size;
    float* out = (float*)d_out;
    zero_kernel<<<1, 64, 0, stream>>>(out, out_size);
    rskf_kernel<<<NSER/64, 64, 0, stream>>>(
        (const float*)d_in[0], (const float*)d_in[1], (const float*)d_in[2],
        (const float*)d_in[3], (const float*)d_in[4], (const float*)d_in[5],
        (const float*)d_in[6], (const float*)d_in[7], (const float*)d_in[8],
        out);
}

// Round 3
// 475.969 us; speedup vs baseline: 1.1360x; 1.1360x over previous
//
#include <hip/hip_runtime.h>

#define NSER 8192
#define NTS  400
#define NO   9

__device__ __forceinline__ float frcp(float x){ return __builtin_amdgcn_rcpf(x); }
__device__ __forceinline__ float fexp2(float x){ return __builtin_amdgcn_exp2f(x); }   // 2^x
__device__ __forceinline__ float flog2(float x){ return __builtin_amdgcn_logf(x); }    // log2(x)

__global__ void zero_kernel(float* out, int n){
    int i = blockIdx.x*blockDim.x + threadIdx.x;
    if (i < n) out[i] = 0.f;
}

// One thread = one series. Exact-algebra streamlined version:
//  - Woodbury (rank-3 disjoint) for regime 1, Sherman-Morrison for regime 2
//  - merged single-pass covariance mixing (exact, sigma = pt1+pt2 kept)
//  - base-2 transcendentals (v_exp_f32/v_log_f32), log-sum accumulated in base 2
__global__ __launch_bounds__(64, 1)
void rskf_kernel(const float* __restrict__ y,   // (N, NT, O)
                 const float* __restrict__ B1,  // 3x3
                 const float* __restrict__ B2,  // 1
                 const float* __restrict__ l1,  // 6
                 const float* __restrict__ l2,  // 8
                 const float* __restrict__ lq,  // 4
                 const float* __restrict__ lr,  // 9
                 const float* __restrict__ g0p, // 1
                 const float* __restrict__ gc,  // 3
                 float* __restrict__ out)
{
    const int n = blockIdx.x*64 + (int)threadIdx.x;

    const float L2E = 1.4426950408889634f;   // log2(e)
    const float LN2 = 0.6931471805599453f;
    const float K2  = 0.5f*L2E;
    const float LOG2PI = 1.8378770664093453f; // ln(2*pi)

    // ---- uniform parameter prep (wave-uniform -> SGPRs) ----
    float Bm[3][3];
    #pragma unroll
    for (int i=0;i<3;++i)
        #pragma unroll
        for (int j=0;j<3;++j) Bm[i][j] = B1[i*3+j];
    const float b2 = B2[0];
    float qd[4];
    #pragma unroll
    for (int i=0;i<4;++i) qd[i] = fexp2(lq[i]*L2E);

    float c[9];
    c[0]=1.f; c[1]=l1[0]; c[2]=l1[1];
    c[3]=1.f; c[4]=l1[2]; c[5]=l1[3];
    c[6]=1.f; c[7]=l1[4]; c[8]=l1[5];
    float mv[9]; mv[0]=1.f;
    #pragma unroll
    for (int o=1;o<9;++o) mv[o]=l2[o-1];

    float invD[9];
    float logdetD2 = 0.f;   // log2 det D
    #pragma unroll
    for (int o=0;o<9;++o){
        float D  = fexp2(lr[o]*L2E) + 1e-6f;   // R diag + jitter
        logdetD2 += flog2(D);
        invD[o]  = 1.f/D;
    }
    const float s0 = invD[0] + c[1]*c[1]*invD[1] + c[2]*c[2]*invD[2];
    const float s1 = invD[3] + c[4]*c[4]*invD[4] + c[5]*c[5]*invD[5];
    const float s2 = invD[6] + c[7]*c[7]*invD[7] + c[8]*c[8]*invD[8];
    float smm = 0.f;
    #pragma unroll
    for (int o=0;o<9;++o) smm += mv[o]*mv[o]*invD[o];
    const float invs0=1.f/s0, invs1=1.f/s1, invs2=1.f/s2;
    // C2f2 = 0.5*log2 of (2pi)^9 * detD ; C1f2 adds 0.5*log2(s0 s1 s2)
    const float C2f2 = 0.5f*(9.f*LOG2PI*L2E + logdetD2);
    const float C1f2 = C2f2 + 0.5f*(flog2(s0)+flog2(s1)+flog2(s2));
    const float g0L  = g0p[0]*L2E;
    const float gcL0 = gc[0]*L2E, gcL1 = gc[1]*L2E, gcL2 = gc[2]*L2E;

    // ---- state ----
    float prob1=0.99f, prob2=0.01f;
    float eta0=0.f, eta1v=0.f, eta2v=0.f, eta3=0.f;
    float P[4][4];
    #pragma unroll
    for (int i=0;i<4;++i)
        #pragma unroll
        for (int j=0;j<4;++j) P[i][j] = (i==j)?1000.f:0.f;

    const float* __restrict__ yp = y + (size_t)n*(NTS*NO);
    float ynx[9];
    #pragma unroll
    for (int o=0;o<9;++o) ynx[o]=yp[o];
    float acc2=0.f;   // accumulates -log2(marg)

    #pragma unroll 2
    for (int t=0;t<NTS;++t){
        float yc[9];
        #pragma unroll
        for (int o=0;o<9;++o) yc[o]=ynx[o];
        const int tn = (t+1<NTS)?(t+1):t;
        const float* ypn = yp + tn*NO;
        #pragma unroll
        for (int o=0;o<9;++o) ynx[o]=ypn[o];

        // regime transition probability (base-2 sigmoid)
        float lg = fmaf(gcL2, eta2v, fmaf(gcL1, eta1v, fmaf(gcL0, eta0, g0L)));
        float p11 = frcp(1.f + fexp2(-lg));

        // predict mean
        float ep0 = fmaf(Bm[0][2],eta2v, fmaf(Bm[0][1],eta1v, Bm[0][0]*eta0));
        float ep1 = fmaf(Bm[1][2],eta2v, fmaf(Bm[1][1],eta1v, Bm[1][0]*eta0));
        float ep2 = fmaf(Bm[2][2],eta2v, fmaf(Bm[2][1],eta1v, Bm[2][0]*eta0));
        float ep3 = b2*eta3;

        // predict covariance: Pp = B P B^T + Q
        float Tm[4][4];
        #pragma unroll
        for (int i=0;i<3;++i)
            #pragma unroll
            for (int j=0;j<4;++j)
                Tm[i][j] = fmaf(Bm[i][2],P[2][j], fmaf(Bm[i][1],P[1][j], Bm[i][0]*P[0][j]));
        #pragma unroll
        for (int j=0;j<4;++j) Tm[3][j] = b2*P[3][j];
        float Pp[4][4];
        #pragma unroll
        for (int i=0;i<4;++i)
            #pragma unroll
            for (int j=i;j<4;++j){
                float v;
                if (j<3) v = fmaf(Tm[i][2],Bm[j][2], fmaf(Tm[i][1],Bm[j][1], Tm[i][0]*Bm[j][0]));
                else     v = Tm[i][3]*b2;
                Pp[i][j]=v; Pp[j][i]=v;
            }
        Pp[0][0]+=qd[0]; Pp[1][1]+=qd[1]; Pp[2][2]+=qd[2]; Pp[3][3]+=qd[3];

        // ================= regime 1 (Woodbury, rank-3 disjoint) =================
        float v1[9];
        v1[0]=yc[0]-ep0;            v1[1]=fmaf(-c[1],ep0,yc[1]); v1[2]=fmaf(-c[2],ep0,yc[2]);
        v1[3]=yc[3]-ep1;            v1[4]=fmaf(-c[4],ep1,yc[4]); v1[5]=fmaf(-c[5],ep1,yc[5]);
        v1[6]=yc[6]-ep2;            v1[7]=fmaf(-c[7],ep2,yc[7]); v1[8]=fmaf(-c[8],ep2,yc[8]);
        float z[9];
        #pragma unroll
        for (int o=0;o<9;++o) z[o]=invD[o]*v1[o];
        // pairwise tree for t0 = z.v1
        float ta = fmaf(z[1],v1[1], z[0]*v1[0]);
        float tb = fmaf(z[3],v1[3], z[2]*v1[2]);
        float tc = fmaf(z[5],v1[5], z[4]*v1[4]);
        float td = fmaf(z[7],v1[7], z[6]*v1[6]);
        float t0 = (ta+tb) + (tc+td) + z[8]*v1[8];
        float u0 = fmaf(c[2],z[2], fmaf(c[1],z[1], z[0]));
        float u1 = fmaf(c[5],z[5], fmaf(c[4],z[4], z[3]));
        float u2 = fmaf(c[8],z[8], fmaf(c[7],z[7], z[6]));
        float ub0=u0*invs0, ub1=u1*invs1, ub2=u2*invs2;
        // A3 = P3 + S^-1 ; M1 = A3^-1 (symmetric 3x3 adjugate)
        float a00=Pp[0][0]+invs0, a01=Pp[0][1], a02=Pp[0][2];
        float a11=Pp[1][1]+invs1, a12=Pp[1][2], a22=Pp[2][2]+invs2;
        float i00 = fmaf(a11,a22, -a12*a12);
        float i01 = fmaf(a02,a12, -a01*a22);
        float i02 = fmaf(a01,a12, -a02*a11);
        float det = fmaf(a00,i00, fmaf(a01,i01, a02*i02));
        float i11 = fmaf(a00,a22, -a02*a02);
        float i12 = fmaf(a01,a02, -a00*a12);
        float i22 = fmaf(a00,a11, -a01*a01);
        float idet = frcp(det);
        float m00=i00*idet, m01=i01*idet, m02=i02*idet;
        float m11=i11*idet, m12=i12*idet, m22=i22*idet;
        float w0 = fmaf(m02,ub2, fmaf(m01,ub1, m00*ub0));
        float w1 = fmaf(m12,ub2, fmaf(m11,ub1, m01*ub0));
        float w2 = fmaf(m22,ub2, fmaf(m12,ub1, m02*ub0));
        float q1 = t0 - (fmaf(u2,ub2, fmaf(u1,ub1, u0*ub0)))
                      + (fmaf(ub2,w2, fmaf(ub1,w1, ub0*w0)));
        float lik1 = fexp2(fmaf(-0.5f, flog2(det), fmaf(-K2, q1, -C1f2)));

        float e1[4];
        #pragma unroll
        for (int i=0;i<4;++i)
            e1[i] = ( i==0 ? ep0 : i==1 ? ep1 : i==2 ? ep2 : ep3 )
                    + fmaf(Pp[i][2],w2, fmaf(Pp[i][1],w1, Pp[i][0]*w0));
        float T1[4][3];
        #pragma unroll
        for (int i=0;i<4;++i){
            T1[i][0]=fmaf(Pp[i][2],m02, fmaf(Pp[i][1],m01, Pp[i][0]*m00));
            T1[i][1]=fmaf(Pp[i][2],m12, fmaf(Pp[i][1],m11, Pp[i][0]*m01));
            T1[i][2]=fmaf(Pp[i][2],m22, fmaf(Pp[i][1],m12, Pp[i][0]*m02));
        }
        float S1[4][4];
        #pragma unroll
        for (int i=0;i<4;++i)
            #pragma unroll
            for (int j=i;j<4;++j){
                float v = fmaf(T1[i][2],Pp[j][2], fmaf(T1[i][1],Pp[j][1], T1[i][0]*Pp[j][0]));
                S1[i][j]=v; S1[j][i]=v;
            }

        // ================= regime 2 (Sherman-Morrison, rank-1) =================
        float beta = Pp[3][3];
        float v2[9];
        v2[0]=yc[0]-ep3;
        #pragma unroll
        for (int o=1;o<9;++o) v2[o]=fmaf(-mv[o],ep3,yc[o]);
        float z2[9];
        #pragma unroll
        for (int o=0;o<9;++o) z2[o]=invD[o]*v2[o];
        float sa = fmaf(z2[1],v2[1], z2[0]*v2[0]);
        float sb = fmaf(z2[3],v2[3], z2[2]*v2[2]);
        float sc = fmaf(z2[5],v2[5], z2[4]*v2[4]);
        float sd = fmaf(z2[7],v2[7], z2[6]*v2[6]);
        float t02 = (sa+sb) + (sc+sd) + z2[8]*v2[8];
        float ua = fmaf(mv[1],z2[1], z2[0]);
        float ub_ = fmaf(mv[3],z2[3], mv[2]*z2[2]);
        float uc = fmaf(mv[5],z2[5], mv[4]*z2[4]);
        float ud = fmaf(mv[7],z2[7], mv[6]*z2[6]);
        float uu = (ua+ub_) + (uc+ud) + mv[8]*z2[8];
        float denom = fmaf(beta, smm, 1.f);
        float iden  = frcp(denom);
        float g2v = uu*iden;
        float q2  = fmaf(-beta*uu, g2v, t02);
        float lik2 = fexp2(fmaf(-0.5f, flog2(denom), fmaf(-K2, q2, -C2f2)));
        float e2[4];
        e2[0]=fmaf(Pp[0][3],g2v,ep0); e2[1]=fmaf(Pp[1][3],g2v,ep1);
        e2[2]=fmaf(Pp[2][3],g2v,ep2); e2[3]=fmaf(Pp[3][3],g2v,ep3);
        float k2s = smm*iden;

        // ================= IMM mixing (exact, merged single-pass P) ============
        float pm   = prob1*p11;
        float num1 = lik1*pm;
        float w2f  = (prob1 - pm) + prob2;   // prob1*p12 + prob2
        float num2 = lik2*w2f;
        float marg = num1+num2+1e-9f;
        acc2 -= flog2(marg);
        float imarg = frcp(marg);
        float pt1 = num1*imarg, pt2 = num2*imarg;
        float sig = pt1+pt2;
        float et[4], d1[4], d2[4];
        #pragma unroll
        for (int i=0;i<4;++i) et[i]=fmaf(pt1,e1[i], pt2*e2[i]);
        #pragma unroll
        for (int i=0;i<4;++i){ d1[i]=e1[i]-et[i]; d2[i]=e2[i]-et[i]; }
        float kap = pt2*k2s;
        float p3a[4], da1[4], da2[4];
        #pragma unroll
        for (int i=0;i<4;++i){ p3a[i]=kap*Pp[i][3]; da1[i]=pt1*d1[i]; da2[i]=pt2*d2[i]; }
        #pragma unroll
        for (int i=0;i<4;++i)
            #pragma unroll
            for (int j=i;j<4;++j){
                float v = sig*Pp[i][j];
                v = fmaf(-pt1, S1[i][j], v);
                v = fmaf(-p3a[i], Pp[j][3], v);
                v = fmaf(da1[i], d1[j], v);
                v = fmaf(da2[i], d2[j], v);
                P[i][j]=v; P[j][i]=v;
            }
        prob1=pt1; prob2=pt2;
        eta0=et[0]; eta1v=et[1]; eta2v=et[2]; eta3=et[3];
    }

    float acc = acc2 * LN2;
    #pragma unroll
    for (int off=32; off>0; off>>=1) acc += __shfl_down(acc, off);
    if (threadIdx.x==0) atomicAdd(out, acc);
}

extern "C" void kernel_launch(void* const* d_in, const int* in_sizes, int n_in,
                              void* d_out, int out_size, void* d_ws, size_t ws_size,
                              hipStream_t stream) {
    (void)in_sizes; (void)n_in; (void)d_ws; (void)ws_size;
    float* out = (float*)d_out;
    zero_kernel<<<1, 64, 0, stream>>>(out, out_size);
    rskf_kernel<<<NSER/64, 64, 0, stream>>>(
        (const float*)d_in[0], (const float*)d_in[1], (const float*)d_in[2],
        (const float*)d_in[3], (const float*)d_in[4], (const float*)d_in[5],
        (const float*)d_in[6], (const float*)d_in[7], (const float*)d_in[8],
        out);
}

// Round 4
// 354.410 us; speedup vs baseline: 1.5257x; 1.3430x over previous
//
#include <hip/hip_runtime.h>

#define NSER 8192
#define NTS  400
#define NO   9

__device__ __forceinline__ float frcp(float x){ return __builtin_amdgcn_rcpf(x); }
__device__ __forceinline__ float fexp2(float x){ return __builtin_amdgcn_exp2f(x); }   // 2^x
__device__ __forceinline__ float flog2(float x){ return __builtin_amdgcn_logf(x); }    // log2(x)

__global__ void zero_kernel(float* out, int n){
    int i = blockIdx.x*blockDim.x + threadIdx.x;
    if (i < n) out[i] = 0.f;
}

// One thread = one series.
// Round-4 algebra: closed-form P1 (S^-1 - S^-1 W S^-1 structure), gain via
// P3*w = ub - invs*w, Delta-form IMM mixing (pt1 d1d1' + pt2 d2d2' = pt1 pt2 sig DD').
__global__ __launch_bounds__(64, 1)
void rskf_kernel(const float* __restrict__ y,   // (N, NT, O)
                 const float* __restrict__ B1,  // 3x3
                 const float* __restrict__ B2,  // 1
                 const float* __restrict__ l1,  // 6
                 const float* __restrict__ l2,  // 8
                 const float* __restrict__ lq,  // 4
                 const float* __restrict__ lr,  // 9
                 const float* __restrict__ g0p, // 1
                 const float* __restrict__ gc,  // 3
                 float* __restrict__ out)
{
    const int n = blockIdx.x*64 + (int)threadIdx.x;

    const float L2E = 1.4426950408889634f;   // log2(e)
    const float LN2 = 0.6931471805599453f;
    const float K2  = 0.5f*L2E;
    const float LOG2PI = 1.8378770664093453f; // ln(2*pi)

    // ---- uniform parameter prep (wave-uniform -> SGPRs) ----
    float Bm[3][3];
    #pragma unroll
    for (int i=0;i<3;++i)
        #pragma unroll
        for (int j=0;j<3;++j) Bm[i][j] = B1[i*3+j];
    const float b2 = B2[0];
    const float b2sq = b2*b2;
    float Bb[3][3];
    #pragma unroll
    for (int i=0;i<3;++i)
        #pragma unroll
        for (int j=0;j<3;++j) Bb[i][j] = b2*Bm[i][j];
    float qd[4];
    #pragma unroll
    for (int i=0;i<4;++i) qd[i] = fexp2(lq[i]*L2E);

    float c[9];
    c[0]=1.f; c[1]=l1[0]; c[2]=l1[1];
    c[3]=1.f; c[4]=l1[2]; c[5]=l1[3];
    c[6]=1.f; c[7]=l1[4]; c[8]=l1[5];
    float mv[9]; mv[0]=1.f;
    #pragma unroll
    for (int o=1;o<9;++o) mv[o]=l2[o-1];

    float invD[9];
    float logdetD2 = 0.f;   // log2 det D
    #pragma unroll
    for (int o=0;o<9;++o){
        float D  = fexp2(lr[o]*L2E) + 1e-6f;   // R diag + jitter
        logdetD2 += flog2(D);
        invD[o]  = 1.f/D;
    }
    const float s0 = invD[0] + c[1]*c[1]*invD[1] + c[2]*c[2]*invD[2];
    const float s1 = invD[3] + c[4]*c[4]*invD[4] + c[5]*c[5]*invD[5];
    const float s2 = invD[6] + c[7]*c[7]*invD[7] + c[8]*c[8]*invD[8];
    float smm = 0.f;
    #pragma unroll
    for (int o=0;o<9;++o) smm += mv[o]*mv[o]*invD[o];
    const float invs0=1.f/s0, invs1=1.f/s1, invs2=1.f/s2;
    // invs_i*invs_j for the S^-1 W S^-1 entries
    const float k00=invs0*invs0, k01=invs0*invs1, k02=invs0*invs2;
    const float k11=invs1*invs1, k12=invs1*invs2, k22=invs2*invs2;
    const float C2f2 = 0.5f*(9.f*LOG2PI*L2E + logdetD2);
    const float C1f2 = C2f2 + 0.5f*(flog2(s0)+flog2(s1)+flog2(s2));
    const float g0L  = g0p[0]*L2E;
    const float gcL0 = gc[0]*L2E, gcL1 = gc[1]*L2E, gcL2 = gc[2]*L2E;

    // ---- state ----
    float prob1=0.99f, prob2=0.01f;
    float eta0=0.f, eta1v=0.f, eta2v=0.f, eta3=0.f;
    float P[4][4];
    #pragma unroll
    for (int i=0;i<4;++i)
        #pragma unroll
        for (int j=0;j<4;++j) P[i][j] = (i==j)?1000.f:0.f;

    const float* __restrict__ yp = y + (size_t)n*(NTS*NO);
    float ynx[9];
    #pragma unroll
    for (int o=0;o<9;++o) ynx[o]=yp[o];
    float acc2=0.f;   // accumulates -log2(marg)

    #pragma unroll 2
    for (int t=0;t<NTS;++t){
        float yc[9];
        #pragma unroll
        for (int o=0;o<9;++o) yc[o]=ynx[o];
        const int tn = (t+1<NTS)?(t+1):t;
        const float* ypn = yp + tn*NO;
        #pragma unroll
        for (int o=0;o<9;++o) ynx[o]=ypn[o];

        // regime transition probability (base-2 sigmoid)
        float lg = fmaf(gcL2, eta2v, fmaf(gcL1, eta1v, fmaf(gcL0, eta0, g0L)));
        float p11 = frcp(1.f + fexp2(-lg));

        // predict mean
        float ep0 = fmaf(Bm[0][2],eta2v, fmaf(Bm[0][1],eta1v, Bm[0][0]*eta0));
        float ep1 = fmaf(Bm[1][2],eta2v, fmaf(Bm[1][1],eta1v, Bm[1][0]*eta0));
        float ep2 = fmaf(Bm[2][2],eta2v, fmaf(Bm[2][1],eta1v, Bm[2][0]*eta0));
        float ep3 = b2*eta3;

        // predict covariance: Pp = B P B^T + Q (block structure)
        float U[3][3];
        #pragma unroll
        for (int i=0;i<3;++i)
            #pragma unroll
            for (int k=0;k<3;++k)
                U[i][k] = fmaf(Bm[i][2],P[2][k], fmaf(Bm[i][1],P[1][k], Bm[i][0]*P[0][k]));
        float Pp[4][4];
        #pragma unroll
        for (int i=0;i<3;++i)
            #pragma unroll
            for (int j=i;j<3;++j){
                float v = fmaf(U[i][2],Bm[j][2], fmaf(U[i][1],Bm[j][1], U[i][0]*Bm[j][0]));
                Pp[i][j]=v; Pp[j][i]=v;
            }
        #pragma unroll
        for (int i=0;i<3;++i){
            float v = fmaf(Bb[i][2],P[2][3], fmaf(Bb[i][1],P[1][3], Bb[i][0]*P[0][3]));
            Pp[i][3]=v; Pp[3][i]=v;
        }
        Pp[0][0]+=qd[0]; Pp[1][1]+=qd[1]; Pp[2][2]+=qd[2];
        Pp[3][3] = fmaf(b2sq, P[3][3], qd[3]);

        // ================= regime 1 (Woodbury, rank-3 disjoint) =================
        float v1[9];
        v1[0]=yc[0]-ep0;            v1[1]=fmaf(-c[1],ep0,yc[1]); v1[2]=fmaf(-c[2],ep0,yc[2]);
        v1[3]=yc[3]-ep1;            v1[4]=fmaf(-c[4],ep1,yc[4]); v1[5]=fmaf(-c[5],ep1,yc[5]);
        v1[6]=yc[6]-ep2;            v1[7]=fmaf(-c[7],ep2,yc[7]); v1[8]=fmaf(-c[8],ep2,yc[8]);
        float z[9];
        #pragma unroll
        for (int o=0;o<9;++o) z[o]=invD[o]*v1[o];
        float ta = fmaf(z[1],v1[1], z[0]*v1[0]);
        float tb = fmaf(z[3],v1[3], z[2]*v1[2]);
        float tc = fmaf(z[5],v1[5], z[4]*v1[4]);
        float td = fmaf(z[7],v1[7], z[6]*v1[6]);
        float t0 = (ta+tb) + (tc+td) + z[8]*v1[8];
        float u0 = fmaf(c[2],z[2], fmaf(c[1],z[1], z[0]));
        float u1 = fmaf(c[5],z[5], fmaf(c[4],z[4], z[3]));
        float u2 = fmaf(c[8],z[8], fmaf(c[7],z[7], z[6]));
        float ub0=u0*invs0, ub1=u1*invs1, ub2=u2*invs2;
        // A3 = P3 + S^-1 ; adjugate + det
        float a00=Pp[0][0]+invs0, a01=Pp[0][1], a02=Pp[0][2];
        float a11=Pp[1][1]+invs1, a12=Pp[1][2], a22=Pp[2][2]+invs2;
        float i00 = fmaf(a11,a22, -a12*a12);
        float i01 = fmaf(a02,a12, -a01*a22);
        float i02 = fmaf(a01,a12, -a02*a11);
        float det = fmaf(a00,i00, fmaf(a01,i01, a02*i02));
        float i11 = fmaf(a00,a22, -a02*a02);
        float i12 = fmaf(a01,a02, -a00*a12);
        float i22 = fmaf(a00,a11, -a01*a01);
        float idet = frcp(det);
        // w = W*ub = idet*(adj*ub)
        float aw0 = fmaf(i02,ub2, fmaf(i01,ub1, i00*ub0));
        float aw1 = fmaf(i12,ub2, fmaf(i11,ub1, i01*ub0));
        float aw2 = fmaf(i22,ub2, fmaf(i12,ub1, i02*ub0));
        float w0=aw0*idet, w1=aw1*idet, w2=aw2*idet;
        float q1 = t0 - (fmaf(u2,ub2, fmaf(u1,ub1, u0*ub0)))
                      + (fmaf(ub2,w2, fmaf(ub1,w1, ub0*w0)));
        float lik1 = fexp2(fmaf(-0.5f, flog2(det), fmaf(-K2, q1, -C1f2)));

        // h = W*p_b, p_b = Pp[0:3][3]
        float pb0=Pp[0][3], pb1=Pp[1][3], pb2=Pp[2][3];
        float ah0 = fmaf(i02,pb2, fmaf(i01,pb1, i00*pb0));
        float ah1 = fmaf(i12,pb2, fmaf(i11,pb1, i01*pb0));
        float ah2 = fmaf(i22,pb2, fmaf(i12,pb1, i02*pb0));
        float h0=ah0*idet, h1=ah1*idet, h2=ah2*idet;

        // e1 = ep + Cp*w : rows 0..2 via P3*w = ub - invs*w
        float e1_0 = fmaf(-invs0, w0, ep0+ub0);
        float e1_1 = fmaf(-invs1, w1, ep1+ub1);
        float e1_2 = fmaf(-invs2, w2, ep2+ub2);
        float e1_3 = ep3 + fmaf(pb2,w2, fmaf(pb1,w1, pb0*w0));

        // P1 closed form
        float P1_00 = fmaf(-(k00*i00), idet, invs0);
        float P1_01 = -(k01*i01)*idet;
        float P1_02 = -(k02*i02)*idet;
        float P1_11 = fmaf(-(k11*i11), idet, invs1);
        float P1_12 = -(k12*i12)*idet;
        float P1_22 = fmaf(-(k22*i22), idet, invs2);
        float P1_03 = invs0*h0, P1_13 = invs1*h1, P1_23 = invs2*h2;
        float P1_33 = Pp[3][3] - fmaf(pb2,h2, fmaf(pb1,h1, pb0*h0));

        // ================= regime 2 (Sherman-Morrison, rank-1) =================
        float beta = Pp[3][3];
        float v2[9];
        v2[0]=yc[0]-ep3;
        #pragma unroll
        for (int o=1;o<9;++o) v2[o]=fmaf(-mv[o],ep3,yc[o]);
        float z2[9];
        #pragma unroll
        for (int o=0;o<9;++o) z2[o]=invD[o]*v2[o];
        float sa = fmaf(z2[1],v2[1], z2[0]*v2[0]);
        float sb = fmaf(z2[3],v2[3], z2[2]*v2[2]);
        float sc = fmaf(z2[5],v2[5], z2[4]*v2[4]);
        float sd = fmaf(z2[7],v2[7], z2[6]*v2[6]);
        float t02 = (sa+sb) + (sc+sd) + z2[8]*v2[8];
        float ua = fmaf(mv[1],z2[1], z2[0]);
        float ub_ = fmaf(mv[3],z2[3], mv[2]*z2[2]);
        float uc = fmaf(mv[5],z2[5], mv[4]*z2[4]);
        float ud = fmaf(mv[7],z2[7], mv[6]*z2[6]);
        float uu = (ua+ub_) + (uc+ud) + mv[8]*z2[8];
        float denom = fmaf(beta, smm, 1.f);
        float iden  = frcp(denom);
        float g2v = uu*iden;
        float q2  = fmaf(-beta*uu, g2v, t02);
        float lik2 = fexp2(fmaf(-0.5f, flog2(denom), fmaf(-K2, q2, -C2f2)));
        float e2_0=fmaf(Pp[0][3],g2v,ep0), e2_1=fmaf(Pp[1][3],g2v,ep1);
        float e2_2=fmaf(Pp[2][3],g2v,ep2), e2_3=fmaf(Pp[3][3],g2v,ep3);
        float k2s = smm*iden;

        // ================= IMM mixing (Delta form) =============================
        float pm   = prob1*p11;
        float num1 = lik1*pm;
        float w2f  = (prob1 - pm) + prob2;   // prob1*p12 + prob2
        float num2 = lik2*w2f;
        float marg = num1+num2+1e-9f;
        acc2 -= flog2(marg);
        float imarg = frcp(marg);
        float pt1 = num1*imarg, pt2 = num2*imarg;
        float sig = pt1+pt2;
        float c3  = (pt1*pt2)*sig;
        float D0=e1_0-e2_0, D1=e1_1-e2_1, D2=e1_2-e2_2, D3=e1_3-e2_3;
        float cd0=c3*D0, cd1=c3*D1, cd2=c3*D2, cd3=c3*D3;
        float et0 = fmaf(pt1, D0, sig*e2_0);
        float et1 = fmaf(pt1, D1, sig*e2_1);
        float et2 = fmaf(pt1, D2, sig*e2_2);
        float et3 = fmaf(pt1, D3, sig*e2_3);
        float kap = pt2*k2s;
        float p3a0=kap*Pp[0][3], p3a1=kap*Pp[1][3], p3a2=kap*Pp[2][3], p3a3=kap*Pp[3][3];

        // P = pt1*P1 + pt2*Pp - kap*pcol pcol^T + c3*D D^T   (upper triangle)
        {
            float v;
            v = fmaf(cd0,D0, fmaf(-p3a0,Pp[0][3], fmaf(pt1,P1_00, pt2*Pp[0][0]))); P[0][0]=v;
            v = fmaf(cd0,D1, fmaf(-p3a0,Pp[1][3], fmaf(pt1,P1_01, pt2*Pp[0][1]))); P[0][1]=v; P[1][0]=v;
            v = fmaf(cd0,D2, fmaf(-p3a0,Pp[2][3], fmaf(pt1,P1_02, pt2*Pp[0][2]))); P[0][2]=v; P[2][0]=v;
            v = fmaf(cd0,D3, fmaf(-p3a0,Pp[3][3], fmaf(pt1,P1_03, pt2*Pp[0][3]))); P[0][3]=v; P[3][0]=v;
            v = fmaf(cd1,D1, fmaf(-p3a1,Pp[1][3], fmaf(pt1,P1_11, pt2*Pp[1][1]))); P[1][1]=v;
            v = fmaf(cd1,D2, fmaf(-p3a1,Pp[2][3], fmaf(pt1,P1_12, pt2*Pp[1][2]))); P[1][2]=v; P[2][1]=v;
            v = fmaf(cd1,D3, fmaf(-p3a1,Pp[3][3], fmaf(pt1,P1_13, pt2*Pp[1][3]))); P[1][3]=v; P[3][1]=v;
            v = fmaf(cd2,D2, fmaf(-p3a2,Pp[2][3], fmaf(pt1,P1_22, pt2*Pp[2][2]))); P[2][2]=v;
            v = fmaf(cd2,D3, fmaf(-p3a2,Pp[3][3], fmaf(pt1,P1_23, pt2*Pp[2][3]))); P[2][3]=v; P[3][2]=v;
            v = fmaf(cd3,D3, fmaf(-p3a3,Pp[3][3], fmaf(pt1,P1_33, pt2*Pp[3][3]))); P[3][3]=v;
        }
        prob1=pt1; prob2=pt2;
        eta0=et0; eta1v=et1; eta2v=et2; eta3=et3;
    }

    float acc = acc2 * LN2;
    #pragma unroll
    for (int off=32; off>0; off>>=1) acc += __shfl_down(acc, off);
    if (threadIdx.x==0) atomicAdd(out, acc);
}

extern "C" void kernel_launch(void* const* d_in, const int* in_sizes, int n_in,
                              void* d_out, int out_size, void* d_ws, size_t ws_size,
                              hipStream_t stream) {
    (void)in_sizes; (void)n_in; (void)d_ws; (void)ws_size;
    float* out = (float*)d_out;
    zero_kernel<<<1, 64, 0, stream>>>(out, out_size);
    rskf_kernel<<<NSER/64, 64, 0, stream>>>(
        (const float*)d_in[0], (const float*)d_in[1], (const float*)d_in[2],
        (const float*)d_in[3], (const float*)d_in[4], (const float*)d_in[5],
        (const float*)d_in[6], (const float*)d_in[7], (const float*)d_in[8],
        out);
}